// Round 8
// baseline (61.605 us; speedup 1.0000x reference)
//
#include <hip/hip_runtime.h>
#include <hip/hip_bf16.h>

typedef __attribute__((ext_vector_type(8))) short short8;
typedef __attribute__((ext_vector_type(4))) float f32x4;

#define LOG2E 1.4426950408889634f
#define PI_F 3.14159265358979323846f
#define NTOT 65536
#define BTOT 2048
#define DIM 64
#define NSPL 256         /* n-splits of 256 cols each */
#define NSTEP 16         /* 256 cols / 16 per MFMA step */
#define NTILES 512       /* NTOT / 128 (prep) */

/* ws layout (bytes) */
#define OFF_SVSBF 0u
#define OFF_XBF   8388608u
#define OFF_EB2   8650752u
#define OFF_A2    8912896u
#define OFF_PART  8921088u
#define WS_NEEDED 11018240u   /* OFF_PART + 256*2048*4 */

__device__ __forceinline__ unsigned short f2bf(float f) {
    union { __hip_bfloat16 h; unsigned short u; } c;
    c.h = __float2bfloat16(f);
    return c.u;
}

// ---------------- prepass: f32 -> bf16 (+norm factors) ----------------
__global__ __launch_bounds__(256) void kde_prep(
    const float* __restrict__ X, const float* __restrict__ svs,
    const float* __restrict__ scale_p, unsigned short* __restrict__ svs_bf,
    unsigned short* __restrict__ x_bf, float* __restrict__ eb2,
    float* __restrict__ a2nat) {
    const float scale = scale_p[0];
    const int tid = threadIdx.x;
    const int blk = blockIdx.x;
    if (blk < NTILES) {
#pragma unroll
        for (int i = 0; i < 4; ++i) {
            int g = i * 256 + tid;
            int row = g >> 3, grp = g & 7;
            const float* src = svs + ((size_t)blk * 128 + row) * DIM + grp * 8;
            float4 v0 = *(const float4*)src;
            float4 v1 = *(const float4*)(src + 4);
            float ss = v0.x * v0.x + v0.y * v0.y + v0.z * v0.z + v0.w * v0.w +
                       v1.x * v1.x + v1.y * v1.y + v1.z * v1.z + v1.w * v1.w;
            short8 o;
            o[0] = f2bf(v0.x); o[1] = f2bf(v0.y); o[2] = f2bf(v0.z); o[3] = f2bf(v0.w);
            o[4] = f2bf(v1.x); o[5] = f2bf(v1.y); o[6] = f2bf(v1.z); o[7] = f2bf(v1.w);
            *(short8*)(svs_bf + (size_t)blk * 8192 + row * 64 + grp * 8) = o;
            ss += __shfl_xor(ss, 1, 64);
            ss += __shfl_xor(ss, 2, 64);
            ss += __shfl_xor(ss, 4, 64);
            if (grp == 0)
                eb2[blk * 128 + row] = __builtin_amdgcn_exp2f(-scale * LOG2E * ss);
        }
    } else {
        const int t16 = blk - NTILES;
        const float C1 = 2.0f * scale * LOG2E;
#pragma unroll
        for (int i = 0; i < 4; ++i) {
            int g = i * 256 + tid;
            int row = g >> 3, grp = g & 7;
            const float* src = X + ((size_t)t16 * 128 + row) * DIM + grp * 8;
            float4 v0 = *(const float4*)src;
            float4 v1 = *(const float4*)(src + 4);
            float ss = v0.x * v0.x + v0.y * v0.y + v0.z * v0.z + v0.w * v0.w +
                       v1.x * v1.x + v1.y * v1.y + v1.z * v1.z + v1.w * v1.w;
            short8 o;
            o[0] = f2bf(v0.x * C1); o[1] = f2bf(v0.y * C1);
            o[2] = f2bf(v0.z * C1); o[3] = f2bf(v0.w * C1);
            o[4] = f2bf(v1.x * C1); o[5] = f2bf(v1.y * C1);
            o[6] = f2bf(v1.z * C1); o[7] = f2bf(v1.w * C1);
            *(short8*)(x_bf + ((size_t)t16 * 128 + row) * 64 + grp * 8) = o;
            ss += __shfl_xor(ss, 1, 64);
            ss += __shfl_xor(ss, 2, 64);
            ss += __shfl_xor(ss, 4, 64);
            if (grp == 0) a2nat[t16 * 128 + row] = -scale * ss;
        }
    }
}

// ---------------- main: barrier-free, register-direct MFMA ----------------
// 2048 blocks x 4 waves = 8192 waves; each wave independently owns
// 64 M-rows x 256 N-cols. B fragments straight from L2 (XCD-clustered, ~1 MB
// per-XCD working set), depth-1 rotation prefetch (r5's proven 40-VGPR body),
// no LDS, no barriers — 8 waves/SIMD of TLP is the latency-hiding.
__global__ __launch_bounds__(256) void kde_main8(
    const unsigned short* __restrict__ svs_bf,
    const unsigned short* __restrict__ x_bf, const float* __restrict__ eb2,
    float* __restrict__ partials) {
    const int tid = threadIdx.x, lane = tid & 63, wave = tid >> 6;
    const int bid = blockIdx.x;             // 0..2047
    const int xcd = bid & 7, j = bid >> 3;  // j 0..255
    const int nsplit = ((j & 31) << 3) | xcd;  // 0..255, clustered per XCD
    const int mgroup = j >> 5;                 // 0..7
    const int rowbase = (mgroup * 4 + wave) * 64;
    const int col = lane & 15, krow = lane >> 4;

    // A fragments: 4 mf x (K=64 as 2 kf)
    short8 afrag[4][2];
#pragma unroll
    for (int mf = 0; mf < 4; ++mf) {
        const unsigned short* ap =
            x_bf + (size_t)(rowbase + mf * 16 + col) * 64 + krow * 8;
#pragma unroll
        for (int kf = 0; kf < 2; ++kf)
            afrag[mf][kf] = *(const short8*)(ap + kf * 32);
    }

    const unsigned short* bbase = svs_bf + (size_t)nsplit * 256 * 64;
    const float* ebase = eb2 + nsplit * 256;

    const f32x4 zacc = {0.f, 0.f, 0.f, 0.f};
    float s[4][4];
#pragma unroll
    for (int mf = 0; mf < 4; ++mf)
#pragma unroll
        for (int q = 0; q < 4; ++q) s[mf][q] = 0.f;

    // rolling depth-1 prefetch into named register buffers (static indexing)
    const unsigned short* bp0 = bbase + (size_t)col * 64 + krow * 8;
    short8 nb0 = *(const short8*)bp0;
    short8 nb1 = *(const short8*)(bp0 + 32);
    float ne = ebase[col];

#pragma unroll 4
    for (int step = 0; step < NSTEP; ++step) {
        short8 cb0 = nb0, cb1 = nb1;
        float ce = ne;
        int nxt = (step + 1) & (NSTEP - 1);  // last iter reloads step 0 (harmless)
        const unsigned short* bp =
            bbase + (size_t)(nxt * 16 + col) * 64 + krow * 8;
        nb0 = *(const short8*)bp;
        nb1 = *(const short8*)(bp + 32);
        ne = ebase[nxt * 16 + col];
#pragma unroll
        for (int mf = 0; mf < 4; ++mf) {
            f32x4 acc = __builtin_amdgcn_mfma_f32_16x16x32_bf16(afrag[mf][0],
                                                                cb0, zacc, 0, 0, 0);
            acc = __builtin_amdgcn_mfma_f32_16x16x32_bf16(afrag[mf][1], cb1,
                                                          acc, 0, 0, 0);
            s[mf][0] = __builtin_fmaf(__builtin_amdgcn_exp2f(acc[0]), ce, s[mf][0]);
            s[mf][1] = __builtin_fmaf(__builtin_amdgcn_exp2f(acc[1]), ce, s[mf][1]);
            s[mf][2] = __builtin_fmaf(__builtin_amdgcn_exp2f(acc[2]), ce, s[mf][2]);
            s[mf][3] = __builtin_fmaf(__builtin_amdgcn_exp2f(acc[3]), ce, s[mf][3]);
        }
    }

    // sum the 16 col-lanes holding the same output rows
#pragma unroll
    for (int mask = 1; mask < 16; mask <<= 1)
#pragma unroll
        for (int mf = 0; mf < 4; ++mf)
#pragma unroll
            for (int q = 0; q < 4; ++q)
                s[mf][q] += __shfl_xor(s[mf][q], mask, 64);

    if (col == 0) {
#pragma unroll
        for (int mf = 0; mf < 4; ++mf)
#pragma unroll
            for (int q = 0; q < 4; ++q) {
                int row = rowbase + mf * 16 + krow * 4 + q;
                partials[(size_t)nsplit * BTOT + row] = s[mf][q];
            }
    }
}

__global__ void kde_final8(const float* __restrict__ partials,
                           const float* __restrict__ a2nat,
                           const float* __restrict__ scale_p,
                           float* __restrict__ out) {
    int b = blockIdx.x * 256 + threadIdx.x;
    if (b >= BTOT) return;
    float total = 0.f;
    for (int sidx = 0; sidx < NSPL; ++sidx)
        total += partials[(size_t)sidx * BTOT + b];
    out[b] = logf(total) + a2nat[b] - logf((float)NTOT) +
             32.0f * logf(scale_p[0] / PI_F);
}

// ================= fallback path (round-1, proven) =================
__device__ __forceinline__ int swz(int row, int kbyte) {
    return row * 128 + (kbyte ^ ((row & 7) << 4));
}

__global__ void fb_rownorm(const float* __restrict__ in,
                           const float* __restrict__ scale_p,
                           float* __restrict__ out, int nrows) {
    int t = blockIdx.x * 256 + threadIdx.x;
    int row = t >> 4;
    if (row >= nrows) return;
    int c4 = t & 15;
    float4 v = *(const float4*)&in[(size_t)row * 64 + c4 * 4];
    float ss = v.x * v.x + v.y * v.y + v.z * v.z + v.w * v.w;
    ss += __shfl_xor(ss, 1, 64);
    ss += __shfl_xor(ss, 2, 64);
    ss += __shfl_xor(ss, 4, 64);
    ss += __shfl_xor(ss, 8, 64);
    if (c4 == 0) out[row] = -scale_p[0] * LOG2E * ss;
}

__global__ __launch_bounds__(256) void fb_main(
    const float* __restrict__ X, const float* __restrict__ svs,
    const float* __restrict__ scale_p, const float* __restrict__ a2,
    const float* __restrict__ b2, float* __restrict__ partials) {
    __shared__ __align__(16) unsigned char ldsA[128 * 128];
    __shared__ __align__(16) unsigned char ldsBf[128 * 128];
    const int tid = threadIdx.x, lane = tid & 63, wave = tid >> 6;
    const int rowbase = blockIdx.x * 128, nbase = blockIdx.y * 512;
    const float C1 = 2.0f * scale_p[0] * LOG2E;
    {
        int r16 = tid >> 4, c4 = tid & 15;
        for (int p = 0; p < 8; ++p) {
            int row = p * 16 + r16;
            float4 v = *(const float4*)&X[(size_t)(rowbase + row) * 64 + c4 * 4];
            uint2 pk;
            pk.x = (unsigned)f2bf(v.x) | ((unsigned)f2bf(v.y) << 16);
            pk.y = (unsigned)f2bf(v.z) | ((unsigned)f2bf(v.w) << 16);
            *(uint2*)(ldsA + swz(row, c4 * 8)) = pk;
        }
    }
    __syncthreads();
    short8 afrag[2][2];
    {
        int arow = wave * 32 + (lane & 15);
        int kb = (lane >> 4) * 16;
        for (int mf = 0; mf < 2; ++mf)
            for (int kf = 0; kf < 2; ++kf)
                afrag[mf][kf] = *(const short8*)(ldsA + swz(arow + mf * 16, kb + kf * 64));
    }
    float a2l[2][4];
    for (int mf = 0; mf < 2; ++mf)
        for (int q = 0; q < 4; ++q)
            a2l[mf][q] = a2[rowbase + wave * 32 + mf * 16 + (lane >> 4) * 4 + q];
    float s[2][4] = {{0.f, 0.f, 0.f, 0.f}, {0.f, 0.f, 0.f, 0.f}};
    for (int itq = 0; itq < 4; ++itq) {
        int nb0 = nbase + itq * 128;
        __syncthreads();
        {
            int r16 = tid >> 4, c4 = tid & 15;
            for (int p = 0; p < 8; ++p) {
                int row = p * 16 + r16;
                float4 v = *(const float4*)&svs[(size_t)(nb0 + row) * 64 + c4 * 4];
                uint2 pk;
                pk.x = (unsigned)f2bf(v.x) | ((unsigned)f2bf(v.y) << 16);
                pk.y = (unsigned)f2bf(v.z) | ((unsigned)f2bf(v.w) << 16);
                *(uint2*)(ldsBf + swz(row, c4 * 8)) = pk;
            }
        }
        float b2l[8];
        for (int nf = 0; nf < 8; ++nf)
            b2l[nf] = b2[nb0 + nf * 16 + (lane & 15)];
        __syncthreads();
        for (int nf = 0; nf < 8; ++nf) {
            int brow = nf * 16 + (lane & 15);
            int kb = (lane >> 4) * 16;
            short8 b0 = *(const short8*)(ldsBf + swz(brow, kb));
            short8 b1 = *(const short8*)(ldsBf + swz(brow, kb + 64));
            for (int mf = 0; mf < 2; ++mf) {
                f32x4 acc = {0.f, 0.f, 0.f, 0.f};
                acc = __builtin_amdgcn_mfma_f32_16x16x32_bf16(afrag[mf][0], b0, acc, 0, 0, 0);
                acc = __builtin_amdgcn_mfma_f32_16x16x32_bf16(afrag[mf][1], b1, acc, 0, 0, 0);
                for (int q = 0; q < 4; ++q) {
                    float e = __builtin_fmaf(C1, acc[q], a2l[mf][q]) + b2l[nf];
                    s[mf][q] += __builtin_amdgcn_exp2f(e);
                }
            }
        }
    }
    for (int mask = 1; mask < 16; mask <<= 1)
        for (int mf = 0; mf < 2; ++mf)
            for (int q = 0; q < 4; ++q)
                s[mf][q] += __shfl_xor(s[mf][q], mask, 64);
    if ((lane & 15) == 0) {
        for (int mf = 0; mf < 2; ++mf)
            for (int q = 0; q < 4; ++q) {
                int row = rowbase + wave * 32 + mf * 16 + (lane >> 4) * 4 + q;
                partials[(size_t)blockIdx.y * BTOT + row] = s[mf][q];
            }
    }
}

__global__ void fb_final(const float* __restrict__ partials,
                         const float* __restrict__ scale_p,
                         float* __restrict__ out) {
    int b = blockIdx.x * 256 + threadIdx.x;
    if (b >= BTOT) return;
    float total = 0.f;
    for (int sidx = 0; sidx < 128; ++sidx)
        total += partials[(size_t)sidx * BTOT + b];
    out[b] = logf(total) - logf((float)NTOT) + 32.0f * logf(scale_p[0] / PI_F);
}

extern "C" void kernel_launch(void* const* d_in, const int* in_sizes, int n_in,
                              void* d_out, int out_size, void* d_ws,
                              size_t ws_size, hipStream_t stream) {
    const float* X = (const float*)d_in[0];
    const float* svs = (const float*)d_in[1];
    const float* scale_p = (const float*)d_in[2];
    unsigned char* ws = (unsigned char*)d_ws;

    if (ws_size >= WS_NEEDED) {
        unsigned short* svs_bf = (unsigned short*)(ws + OFF_SVSBF);
        unsigned short* x_bf = (unsigned short*)(ws + OFF_XBF);
        float* eb2 = (float*)(ws + OFF_EB2);
        float* a2nat = (float*)(ws + OFF_A2);
        float* partials = (float*)(ws + OFF_PART);
        kde_prep<<<NTILES + 16, 256, 0, stream>>>(X, svs, scale_p, svs_bf, x_bf,
                                                  eb2, a2nat);
        kde_main8<<<2048, 256, 0, stream>>>(svs_bf, x_bf, eb2, partials);
        kde_final8<<<BTOT / 256, 256, 0, stream>>>(partials, a2nat, scale_p,
                                                   (float*)d_out);
    } else {
        float* wsf = (float*)d_ws;
        float* b2 = wsf;
        float* a2 = wsf + NTOT;
        float* partials = wsf + NTOT + BTOT;
        fb_rownorm<<<(NTOT * 16) / 256, 256, 0, stream>>>(svs, scale_p, b2, NTOT);
        fb_rownorm<<<(BTOT * 16) / 256, 256, 0, stream>>>(X, scale_p, a2, BTOT);
        dim3 grid(BTOT / 128, 128);
        fb_main<<<grid, 256, 0, stream>>>(X, svs, scale_p, a2, b2, partials);
        fb_final<<<BTOT / 256, 256, 0, stream>>>(partials, scale_p, (float*)d_out);
    }
}

// Round 9
// 48.157 us; speedup vs baseline: 1.2793x; 1.2793x over previous
//
#include <hip/hip_runtime.h>
#include <hip/hip_bf16.h>

typedef __attribute__((ext_vector_type(8))) short short8;
typedef __attribute__((ext_vector_type(4))) float f32x4;

#define LOG2E 1.4426950408889634f
#define PI_F 3.14159265358979323846f
#define NTOT 65536
#define BTOT 2048
#define DIM 64
#define NSPL 128         /* n-splits of 512 cols each */
#define NITER 8          /* 64-row B-tiles per split */
#define NTILES 512       /* NTOT / 128 (prep) */

/* ws layout (bytes) */
#define OFF_SVSBF 0u
#define OFF_XBF   8388608u
#define OFF_EB2   8650752u
#define OFF_A2    8912896u
#define OFF_PART  8921088u
#define WS_NEEDED 11018240u   /* OFF_PART + 256*2048*4 */

__device__ __forceinline__ unsigned short f2bf(float f) {
    union { __hip_bfloat16 h; unsigned short u; } c;
    c.h = __float2bfloat16(f);
    return c.u;
}

// ---------------- prepass: f32 -> bf16 (+norm factors) ----------------
// blocks 0..511: svs tile -> bf16, row-local XOR-swizzled (grp^(row&7)) +
//                eb2 = exp(-scale*||y||^2)
// blocks 512..527: X tile -> C1-prescaled bf16 row-major + a2 = -scale*||x||^2
__global__ __launch_bounds__(256) void kde_prep(
    const float* __restrict__ X, const float* __restrict__ svs,
    const float* __restrict__ scale_p, unsigned short* __restrict__ svs_bf,
    unsigned short* __restrict__ x_bf, float* __restrict__ eb2,
    float* __restrict__ a2nat) {
    const float scale = scale_p[0];
    const int tid = threadIdx.x;
    const int blk = blockIdx.x;
    if (blk < NTILES) {
#pragma unroll
        for (int i = 0; i < 4; ++i) {
            int g = i * 256 + tid;
            int row = g >> 3, grp = g & 7;
            const float* src = svs + ((size_t)blk * 128 + row) * DIM + grp * 8;
            float4 v0 = *(const float4*)src;
            float4 v1 = *(const float4*)(src + 4);
            float ss = v0.x * v0.x + v0.y * v0.y + v0.z * v0.z + v0.w * v0.w +
                       v1.x * v1.x + v1.y * v1.y + v1.z * v1.z + v1.w * v1.w;
            short8 o;
            o[0] = f2bf(v0.x); o[1] = f2bf(v0.y); o[2] = f2bf(v0.z); o[3] = f2bf(v0.w);
            o[4] = f2bf(v1.x); o[5] = f2bf(v1.y); o[6] = f2bf(v1.z); o[7] = f2bf(v1.w);
            int dgrp = grp ^ (row & 7);
            *(short8*)(svs_bf + (size_t)blk * 8192 + row * 64 + dgrp * 8) = o;
            ss += __shfl_xor(ss, 1, 64);
            ss += __shfl_xor(ss, 2, 64);
            ss += __shfl_xor(ss, 4, 64);
            if (grp == 0)
                eb2[blk * 128 + row] = __builtin_amdgcn_exp2f(-scale * LOG2E * ss);
        }
    } else {
        const int t16 = blk - NTILES;
        const float C1 = 2.0f * scale * LOG2E;
#pragma unroll
        for (int i = 0; i < 4; ++i) {
            int g = i * 256 + tid;
            int row = g >> 3, grp = g & 7;
            const float* src = X + ((size_t)t16 * 128 + row) * DIM + grp * 8;
            float4 v0 = *(const float4*)src;
            float4 v1 = *(const float4*)(src + 4);
            float ss = v0.x * v0.x + v0.y * v0.y + v0.z * v0.z + v0.w * v0.w +
                       v1.x * v1.x + v1.y * v1.y + v1.z * v1.z + v1.w * v1.w;
            short8 o;
            o[0] = f2bf(v0.x * C1); o[1] = f2bf(v0.y * C1);
            o[2] = f2bf(v0.z * C1); o[3] = f2bf(v0.w * C1);
            o[4] = f2bf(v1.x * C1); o[5] = f2bf(v1.y * C1);
            o[6] = f2bf(v1.z * C1); o[7] = f2bf(v1.w * C1);
            *(short8*)(x_bf + ((size_t)t16 * 128 + row) * 64 + grp * 8) = o;
            ss += __shfl_xor(ss, 1, 64);
            ss += __shfl_xor(ss, 2, 64);
            ss += __shfl_xor(ss, 4, 64);
            if (grp == 0) a2nat[t16 * 128 + row] = -scale * ss;
        }
    }
}

// ---------------- main: DMA-staged LDS MFMA (r2 structure, 2x grid) -------
// 2048 blocks x 512 threads (8 waves: 4M x 2N). Block = 128 M-rows x 512
// N-cols. Per iter: stage 64 B-rows (8 KB, one global_load_lds/thread) into a
// double buffer, counted vmcnt(1) — never drained mid-loop. eb2 folded
// multiplicatively. Swizzled ds_read (XOR loop-invariant per lane).
__global__ __launch_bounds__(512) void kde_main9(
    const unsigned short* __restrict__ svs_bf,
    const unsigned short* __restrict__ x_bf, const float* __restrict__ eb2,
    float* __restrict__ partials) {
    __shared__ __align__(16) unsigned char ldsB[2][8192];
    __shared__ __align__(16) float ebl[512];

    const int tid = threadIdx.x, lane = tid & 63, wave = tid >> 6;
    const int bid = blockIdx.x;             // 0..2047
    const int xcd = bid & 7, j = bid >> 3;  // j 0..255
    const int nsplit = ((j & 15) << 3) | xcd;  // 0..127, clustered per XCD
    const int mtile = j >> 4;                  // 0..15
    const int wm = wave >> 1, wn = wave & 1;   // 4 x 2 wave grid
    const int rowbase = mtile * 128 + wm * 32;
    const int col = lane & 15, krow = lane >> 4;
    const int off0 = (krow ^ (col & 7)) << 4;        // loop-invariant swizzle
    const int off1 = ((krow + 4) ^ (col & 7)) << 4;

    // A fragments: 2 mf x 2 kf, direct from global (prescaled, row-major)
    short8 afrag[2][2];
#pragma unroll
    for (int mf = 0; mf < 2; ++mf) {
        const unsigned short* ap =
            x_bf + (size_t)(rowbase + mf * 16 + col) * 64 + krow * 8;
#pragma unroll
        for (int kf = 0; kf < 2; ++kf)
            afrag[mf][kf] = *(const short8*)(ap + kf * 32);
    }
    asm volatile("s_waitcnt vmcnt(0)" ::: "memory");  // exact ledger below

    // stage eb2 chunk (512 f32): one size-4 load per lane per wave-64-chunk
    {
        const float* gb = eb2 + nsplit * 512 + wave * 64 + lane;
        __builtin_amdgcn_global_load_lds(
            (const __attribute__((address_space(1))) void*)gb,
            (__attribute__((address_space(3))) void*)&ebl[wave * 64], 4, 0, 0);
    }
    const unsigned char* gsv =
        (const unsigned char*)svs_bf + (size_t)nsplit * 65536;
#define STAGE(t_, buf_)                                                           \
    do {                                                                          \
        const unsigned char* gt_ = gsv + (size_t)(t_)*8192 + wave * 1024 + lane * 16; \
        __builtin_amdgcn_global_load_lds(                                         \
            (const __attribute__((address_space(1))) void*)gt_,                   \
            (__attribute__((address_space(3))) void*)&ldsB[buf_][wave * 1024],    \
            16, 0, 0);                                                            \
    } while (0)
    STAGE(0, 0);
    STAGE(1, 1);  // outstanding: eb, S0, S1

    const f32x4 zacc = {0.f, 0.f, 0.f, 0.f};
    float s[2][4] = {{0.f, 0.f, 0.f, 0.f}, {0.f, 0.f, 0.f, 0.f}};

#pragma unroll
    for (int it = 0; it < NITER; ++it) {
        if (it < NITER - 1)
            asm volatile("s_waitcnt vmcnt(1)" ::: "memory");  // tile it landed
        else
            asm volatile("s_waitcnt vmcnt(0)" ::: "memory");
        asm volatile("s_barrier" ::: "memory");  // all waves' stages visible
        const unsigned char* buf = ldsB[it & 1];
#pragma unroll
        for (int nf = 0; nf < 2; ++nf) {
            const int brow = wn * 32 + nf * 16 + col;
            short8 bb0 = *(const short8*)(buf + brow * 128 + off0);
            short8 bb1 = *(const short8*)(buf + brow * 128 + off1);
            float eb2l = ebl[it * 64 + wn * 32 + nf * 16 + col];
#pragma unroll
            for (int mf = 0; mf < 2; ++mf) {
                f32x4 acc = __builtin_amdgcn_mfma_f32_16x16x32_bf16(
                    afrag[mf][0], bb0, zacc, 0, 0, 0);
                acc = __builtin_amdgcn_mfma_f32_16x16x32_bf16(afrag[mf][1], bb1,
                                                              acc, 0, 0, 0);
                s[mf][0] = __builtin_fmaf(__builtin_amdgcn_exp2f(acc[0]), eb2l, s[mf][0]);
                s[mf][1] = __builtin_fmaf(__builtin_amdgcn_exp2f(acc[1]), eb2l, s[mf][1]);
                s[mf][2] = __builtin_fmaf(__builtin_amdgcn_exp2f(acc[2]), eb2l, s[mf][2]);
                s[mf][3] = __builtin_fmaf(__builtin_amdgcn_exp2f(acc[3]), eb2l, s[mf][3]);
            }
        }
        asm volatile("s_barrier" ::: "memory");  // buf consumed by all waves
        if (it + 2 < NITER) STAGE(it + 2, it & 1);
    }
#undef STAGE

    // sum the 16 col-lanes holding the same output rows
#pragma unroll
    for (int mask = 1; mask < 16; mask <<= 1)
#pragma unroll
        for (int mf = 0; mf < 2; ++mf)
#pragma unroll
            for (int q = 0; q < 4; ++q)
                s[mf][q] += __shfl_xor(s[mf][q], mask, 64);

    if (col == 0) {
#pragma unroll
        for (int mf = 0; mf < 2; ++mf)
#pragma unroll
            for (int q = 0; q < 4; ++q) {
                int row = rowbase + mf * 16 + krow * 4 + q;
                partials[(size_t)(nsplit * 2 + wn) * BTOT + row] = s[mf][q];
            }
    }
}

__global__ void kde_final9(const float* __restrict__ partials,
                           const float* __restrict__ a2nat,
                           const float* __restrict__ scale_p,
                           float* __restrict__ out) {
    int b = blockIdx.x * 256 + threadIdx.x;
    if (b >= BTOT) return;
    float total = 0.f;
    for (int sidx = 0; sidx < NSPL * 2; ++sidx)
        total += partials[(size_t)sidx * BTOT + b];
    out[b] = logf(total) + a2nat[b] - logf((float)NTOT) +
             32.0f * logf(scale_p[0] / PI_F);
}

// ================= fallback path (round-1, proven) =================
__device__ __forceinline__ int swz(int row, int kbyte) {
    return row * 128 + (kbyte ^ ((row & 7) << 4));
}

__global__ void fb_rownorm(const float* __restrict__ in,
                           const float* __restrict__ scale_p,
                           float* __restrict__ out, int nrows) {
    int t = blockIdx.x * 256 + threadIdx.x;
    int row = t >> 4;
    if (row >= nrows) return;
    int c4 = t & 15;
    float4 v = *(const float4*)&in[(size_t)row * 64 + c4 * 4];
    float ss = v.x * v.x + v.y * v.y + v.z * v.z + v.w * v.w;
    ss += __shfl_xor(ss, 1, 64);
    ss += __shfl_xor(ss, 2, 64);
    ss += __shfl_xor(ss, 4, 64);
    ss += __shfl_xor(ss, 8, 64);
    if (c4 == 0) out[row] = -scale_p[0] * LOG2E * ss;
}

__global__ __launch_bounds__(256) void fb_main(
    const float* __restrict__ X, const float* __restrict__ svs,
    const float* __restrict__ scale_p, const float* __restrict__ a2,
    const float* __restrict__ b2, float* __restrict__ partials) {
    __shared__ __align__(16) unsigned char ldsA[128 * 128];
    __shared__ __align__(16) unsigned char ldsBf[128 * 128];
    const int tid = threadIdx.x, lane = tid & 63, wave = tid >> 6;
    const int rowbase = blockIdx.x * 128, nbase = blockIdx.y * 512;
    const float C1 = 2.0f * scale_p[0] * LOG2E;
    {
        int r16 = tid >> 4, c4 = tid & 15;
        for (int p = 0; p < 8; ++p) {
            int row = p * 16 + r16;
            float4 v = *(const float4*)&X[(size_t)(rowbase + row) * 64 + c4 * 4];
            uint2 pk;
            pk.x = (unsigned)f2bf(v.x) | ((unsigned)f2bf(v.y) << 16);
            pk.y = (unsigned)f2bf(v.z) | ((unsigned)f2bf(v.w) << 16);
            *(uint2*)(ldsA + swz(row, c4 * 8)) = pk;
        }
    }
    __syncthreads();
    short8 afrag[2][2];
    {
        int arow = wave * 32 + (lane & 15);
        int kb = (lane >> 4) * 16;
        for (int mf = 0; mf < 2; ++mf)
            for (int kf = 0; kf < 2; ++kf)
                afrag[mf][kf] = *(const short8*)(ldsA + swz(arow + mf * 16, kb + kf * 64));
    }
    float a2l[2][4];
    for (int mf = 0; mf < 2; ++mf)
        for (int q = 0; q < 4; ++q)
            a2l[mf][q] = a2[rowbase + wave * 32 + mf * 16 + (lane >> 4) * 4 + q];
    float s[2][4] = {{0.f, 0.f, 0.f, 0.f}, {0.f, 0.f, 0.f, 0.f}};
    for (int itq = 0; itq < 4; ++itq) {
        int nb0 = nbase + itq * 128;
        __syncthreads();
        {
            int r16 = tid >> 4, c4 = tid & 15;
            for (int p = 0; p < 8; ++p) {
                int row = p * 16 + r16;
                float4 v = *(const float4*)&svs[(size_t)(nb0 + row) * 64 + c4 * 4];
                uint2 pk;
                pk.x = (unsigned)f2bf(v.x) | ((unsigned)f2bf(v.y) << 16);
                pk.y = (unsigned)f2bf(v.z) | ((unsigned)f2bf(v.w) << 16);
                *(uint2*)(ldsBf + swz(row, c4 * 8)) = pk;
            }
        }
        float b2l[8];
        for (int nf = 0; nf < 8; ++nf)
            b2l[nf] = b2[nb0 + nf * 16 + (lane & 15)];
        __syncthreads();
        for (int nf = 0; nf < 8; ++nf) {
            int brow = nf * 16 + (lane & 15);
            int kb = (lane >> 4) * 16;
            short8 b0 = *(const short8*)(ldsBf + swz(brow, kb));
            short8 b1 = *(const short8*)(ldsBf + swz(brow, kb + 64));
            for (int mf = 0; mf < 2; ++mf) {
                f32x4 acc = {0.f, 0.f, 0.f, 0.f};
                acc = __builtin_amdgcn_mfma_f32_16x16x32_bf16(afrag[mf][0], b0, acc, 0, 0, 0);
                acc = __builtin_amdgcn_mfma_f32_16x16x32_bf16(afrag[mf][1], b1, acc, 0, 0, 0);
                for (int q = 0; q < 4; ++q) {
                    float e = __builtin_fmaf(C1, acc[q], a2l[mf][q]) + b2l[nf];
                    s[mf][q] += __builtin_amdgcn_exp2f(e);
                }
            }
        }
    }
    for (int mask = 1; mask < 16; mask <<= 1)
        for (int mf = 0; mf < 2; ++mf)
            for (int q = 0; q < 4; ++q)
                s[mf][q] += __shfl_xor(s[mf][q], mask, 64);
    if ((lane & 15) == 0) {
        for (int mf = 0; mf < 2; ++mf)
            for (int q = 0; q < 4; ++q) {
                int row = rowbase + wave * 32 + mf * 16 + (lane >> 4) * 4 + q;
                partials[(size_t)blockIdx.y * BTOT + row] = s[mf][q];
            }
    }
}

__global__ void fb_final(const float* __restrict__ partials,
                         const float* __restrict__ scale_p,
                         float* __restrict__ out) {
    int b = blockIdx.x * 256 + threadIdx.x;
    if (b >= BTOT) return;
    float total = 0.f;
    for (int sidx = 0; sidx < 128; ++sidx)
        total += partials[(size_t)sidx * BTOT + b];
    out[b] = logf(total) - logf((float)NTOT) + 32.0f * logf(scale_p[0] / PI_F);
}

extern "C" void kernel_launch(void* const* d_in, const int* in_sizes, int n_in,
                              void* d_out, int out_size, void* d_ws,
                              size_t ws_size, hipStream_t stream) {
    const float* X = (const float*)d_in[0];
    const float* svs = (const float*)d_in[1];
    const float* scale_p = (const float*)d_in[2];
    unsigned char* ws = (unsigned char*)d_ws;

    if (ws_size >= WS_NEEDED) {
        unsigned short* svs_bf = (unsigned short*)(ws + OFF_SVSBF);
        unsigned short* x_bf = (unsigned short*)(ws + OFF_XBF);
        float* eb2 = (float*)(ws + OFF_EB2);
        float* a2nat = (float*)(ws + OFF_A2);
        float* partials = (float*)(ws + OFF_PART);
        kde_prep<<<NTILES + 16, 256, 0, stream>>>(X, svs, scale_p, svs_bf, x_bf,
                                                  eb2, a2nat);
        kde_main9<<<2048, 512, 0, stream>>>(svs_bf, x_bf, eb2, partials);
        kde_final9<<<BTOT / 256, 256, 0, stream>>>(partials, a2nat, scale_p,
                                                   (float*)d_out);
    } else {
        float* wsf = (float*)d_ws;
        float* b2 = wsf;
        float* a2 = wsf + NTOT;
        float* partials = wsf + NTOT + BTOT;
        fb_rownorm<<<(NTOT * 16) / 256, 256, 0, stream>>>(svs, scale_p, b2, NTOT);
        fb_rownorm<<<(BTOT * 16) / 256, 256, 0, stream>>>(X, scale_p, a2, BTOT);
        dim3 grid(BTOT / 128, 128);
        fb_main<<<grid, 256, 0, stream>>>(X, svs, scale_p, a2, b2, partials);
        fb_final<<<BTOT / 256, 256, 0, stream>>>(partials, scale_p, (float*)d_out);
    }
}

// Round 10
// 46.257 us; speedup vs baseline: 1.3318x; 1.0411x over previous
//
#include <hip/hip_runtime.h>
#include <hip/hip_bf16.h>

typedef __attribute__((ext_vector_type(8))) short short8;
typedef __attribute__((ext_vector_type(4))) float f32x4;

#define LOG2E 1.4426950408889634f
#define PI_F 3.14159265358979323846f
#define NTOT 65536
#define BTOT 2048
#define DIM 64
#define NSPL 128         /* n-splits of 512 cols each */
#define NITER 8          /* 64-row B-tiles per split */
#define NTILES 512       /* NTOT / 128 (prep) */

/* ws layout (bytes) */
#define OFF_SVSBF 0u
#define OFF_XBF   8388608u
#define OFF_EB2   8650752u
#define OFF_A2    8912896u
#define OFF_PART  8921088u
#define WS_NEEDED 11018240u

__device__ __forceinline__ unsigned short f2bf(float f) {
    union { __hip_bfloat16 h; unsigned short u; } c;
    c.h = __float2bfloat16(f);
    return c.u;
}

// ---------------- prepass: f32 -> bf16 (+norm factors) ----------------
// blocks 0..511: svs tile -> bf16, row-local XOR-swizzled (grp^(row&7)) +
//                eb2 = exp(-scale*||y||^2)
// blocks 512..527: X tile -> C1-prescaled bf16 row-major + a2 = -scale*||x||^2
__global__ __launch_bounds__(256) void kde_prep(
    const float* __restrict__ X, const float* __restrict__ svs,
    const float* __restrict__ scale_p, unsigned short* __restrict__ svs_bf,
    unsigned short* __restrict__ x_bf, float* __restrict__ eb2,
    float* __restrict__ a2nat) {
    const float scale = scale_p[0];
    const int tid = threadIdx.x;
    const int blk = blockIdx.x;
    if (blk < NTILES) {
#pragma unroll
        for (int i = 0; i < 4; ++i) {
            int g = i * 256 + tid;
            int row = g >> 3, grp = g & 7;
            const float* src = svs + ((size_t)blk * 128 + row) * DIM + grp * 8;
            float4 v0 = *(const float4*)src;
            float4 v1 = *(const float4*)(src + 4);
            float ss = v0.x * v0.x + v0.y * v0.y + v0.z * v0.z + v0.w * v0.w +
                       v1.x * v1.x + v1.y * v1.y + v1.z * v1.z + v1.w * v1.w;
            short8 o;
            o[0] = f2bf(v0.x); o[1] = f2bf(v0.y); o[2] = f2bf(v0.z); o[3] = f2bf(v0.w);
            o[4] = f2bf(v1.x); o[5] = f2bf(v1.y); o[6] = f2bf(v1.z); o[7] = f2bf(v1.w);
            int dgrp = grp ^ (row & 7);
            *(short8*)(svs_bf + (size_t)blk * 8192 + row * 64 + dgrp * 8) = o;
            ss += __shfl_xor(ss, 1, 64);
            ss += __shfl_xor(ss, 2, 64);
            ss += __shfl_xor(ss, 4, 64);
            if (grp == 0)
                eb2[blk * 128 + row] = __builtin_amdgcn_exp2f(-scale * LOG2E * ss);
        }
    } else {
        const int t16 = blk - NTILES;
        const float C1 = 2.0f * scale * LOG2E;
#pragma unroll
        for (int i = 0; i < 4; ++i) {
            int g = i * 256 + tid;
            int row = g >> 3, grp = g & 7;
            const float* src = X + ((size_t)t16 * 128 + row) * DIM + grp * 8;
            float4 v0 = *(const float4*)src;
            float4 v1 = *(const float4*)(src + 4);
            float ss = v0.x * v0.x + v0.y * v0.y + v0.z * v0.z + v0.w * v0.w +
                       v1.x * v1.x + v1.y * v1.y + v1.z * v1.z + v1.w * v1.w;
            short8 o;
            o[0] = f2bf(v0.x * C1); o[1] = f2bf(v0.y * C1);
            o[2] = f2bf(v0.z * C1); o[3] = f2bf(v0.w * C1);
            o[4] = f2bf(v1.x * C1); o[5] = f2bf(v1.y * C1);
            o[6] = f2bf(v1.z * C1); o[7] = f2bf(v1.w * C1);
            *(short8*)(x_bf + ((size_t)t16 * 128 + row) * 64 + grp * 8) = o;
            ss += __shfl_xor(ss, 1, 64);
            ss += __shfl_xor(ss, 2, 64);
            ss += __shfl_xor(ss, 4, 64);
            if (grp == 0) a2nat[t16 * 128 + row] = -scale * ss;
        }
    }
}

// ---------------- main: DMA-staged LDS MFMA, 4-buffer ring, 1 barrier/iter --
// 2048 blocks x 512 threads (8 waves: 4M x 2N). Block = 128 M x 512 N.
// Ring of 4 x 8KB LDS buffers; STAGE(it+3) targets slot (it-1)&3, which all
// waves finished reading before the single barrier at top of iter `it`
// (ds_read data is consumed by MFMA pre-barrier). Counted vmcnt(2) keeps 3
// stages in flight — never drained mid-loop.
__global__ __launch_bounds__(512) void kde_main10(
    const unsigned short* __restrict__ svs_bf,
    const unsigned short* __restrict__ x_bf, const float* __restrict__ eb2,
    float* __restrict__ partials) {
    __shared__ __align__(16) unsigned char ldsB[4][8192];
    __shared__ __align__(16) float ebl[512];

    const int tid = threadIdx.x, lane = tid & 63, wave = tid >> 6;
    const int bid = blockIdx.x;             // 0..2047
    const int xcd = bid & 7, j = bid >> 3;  // j 0..255
    const int nsplit = ((j & 15) << 3) | xcd;  // 0..127, clustered per XCD
    const int mtile = j >> 4;                  // 0..15
    const int wm = wave >> 1, wn = wave & 1;   // 4 x 2 wave grid
    const int rowbase = mtile * 128 + wm * 32;
    const int col = lane & 15, krow = lane >> 4;
    const int off0 = (krow ^ (col & 7)) << 4;        // loop-invariant swizzle
    const int off1 = ((krow + 4) ^ (col & 7)) << 4;

    // A fragments: 2 mf x 2 kf, direct from global (prescaled, row-major)
    short8 afrag[2][2];
#pragma unroll
    for (int mf = 0; mf < 2; ++mf) {
        const unsigned short* ap =
            x_bf + (size_t)(rowbase + mf * 16 + col) * 64 + krow * 8;
#pragma unroll
        for (int kf = 0; kf < 2; ++kf)
            afrag[mf][kf] = *(const short8*)(ap + kf * 32);
    }
    asm volatile("s_waitcnt vmcnt(0)" ::: "memory");  // exact ledger below

    // stage eb2 chunk (512 f32)
    {
        const float* gb = eb2 + nsplit * 512 + wave * 64 + lane;
        __builtin_amdgcn_global_load_lds(
            (const __attribute__((address_space(1))) void*)gb,
            (__attribute__((address_space(3))) void*)&ebl[wave * 64], 4, 0, 0);
    }
    const unsigned char* gsv =
        (const unsigned char*)svs_bf + (size_t)nsplit * 65536;
#define STAGE(t_)                                                                 \
    do {                                                                          \
        const unsigned char* gt_ = gsv + (size_t)(t_)*8192 + wave * 1024 + lane * 16; \
        __builtin_amdgcn_global_load_lds(                                         \
            (const __attribute__((address_space(1))) void*)gt_,                   \
            (__attribute__((address_space(3))) void*)&ldsB[(t_) & 3][wave * 1024], \
            16, 0, 0);                                                            \
    } while (0)
    STAGE(0);
    STAGE(1);
    STAGE(2);  // outstanding: EB, S0, S1, S2

    const f32x4 zacc = {0.f, 0.f, 0.f, 0.f};
    float s[2][4] = {{0.f, 0.f, 0.f, 0.f}, {0.f, 0.f, 0.f, 0.f}};

#pragma unroll
    for (int it = 0; it < NITER; ++it) {
        // wait for tile `it` (leave the 2 newer stages in flight)
        if (it < 6)
            asm volatile("s_waitcnt vmcnt(2)" ::: "memory");
        else if (it == 6)
            asm volatile("s_waitcnt vmcnt(1)" ::: "memory");
        else
            asm volatile("s_waitcnt vmcnt(0)" ::: "memory");
        asm volatile("s_barrier" ::: "memory");  // all waves' stages visible;
                                                 // also: all waves done it-1
        if (it + 3 < NITER) STAGE(it + 3);       // slot (it-1)&3: free (above)
        const unsigned char* buf = ldsB[it & 3];
#pragma unroll
        for (int nf = 0; nf < 2; ++nf) {
            const int brow = wn * 32 + nf * 16 + col;
            short8 bb0 = *(const short8*)(buf + brow * 128 + off0);
            short8 bb1 = *(const short8*)(buf + brow * 128 + off1);
            float eb2l = ebl[it * 64 + wn * 32 + nf * 16 + col];
#pragma unroll
            for (int mf = 0; mf < 2; ++mf) {
                f32x4 acc = __builtin_amdgcn_mfma_f32_16x16x32_bf16(
                    afrag[mf][0], bb0, zacc, 0, 0, 0);
                acc = __builtin_amdgcn_mfma_f32_16x16x32_bf16(afrag[mf][1], bb1,
                                                              acc, 0, 0, 0);
                s[mf][0] = __builtin_fmaf(__builtin_amdgcn_exp2f(acc[0]), eb2l, s[mf][0]);
                s[mf][1] = __builtin_fmaf(__builtin_amdgcn_exp2f(acc[1]), eb2l, s[mf][1]);
                s[mf][2] = __builtin_fmaf(__builtin_amdgcn_exp2f(acc[2]), eb2l, s[mf][2]);
                s[mf][3] = __builtin_fmaf(__builtin_amdgcn_exp2f(acc[3]), eb2l, s[mf][3]);
            }
        }
    }
#undef STAGE

    // sum the 16 col-lanes holding the same output rows
#pragma unroll
    for (int mask = 1; mask < 16; mask <<= 1)
#pragma unroll
        for (int mf = 0; mf < 2; ++mf)
#pragma unroll
            for (int q = 0; q < 4; ++q)
                s[mf][q] += __shfl_xor(s[mf][q], mask, 64);

    if (col == 0) {
#pragma unroll
        for (int mf = 0; mf < 2; ++mf)
#pragma unroll
            for (int q = 0; q < 4; ++q) {
                int row = rowbase + mf * 16 + krow * 4 + q;
                partials[(size_t)(nsplit * 2 + wn) * BTOT + row] = s[mf][q];
            }
    }
}

__global__ void kde_final10(const float* __restrict__ partials,
                            const float* __restrict__ a2nat,
                            const float* __restrict__ scale_p,
                            float* __restrict__ out) {
    int b = blockIdx.x * 256 + threadIdx.x;
    if (b >= BTOT) return;
    float total = 0.f;
    for (int sidx = 0; sidx < NSPL * 2; ++sidx)
        total += partials[(size_t)sidx * BTOT + b];
    out[b] = logf(total) + a2nat[b] - logf((float)NTOT) +
             32.0f * logf(scale_p[0] / PI_F);
}

// ================= fallback path (round-1, proven) =================
__device__ __forceinline__ int swz(int row, int kbyte) {
    return row * 128 + (kbyte ^ ((row & 7) << 4));
}

__global__ void fb_rownorm(const float* __restrict__ in,
                           const float* __restrict__ scale_p,
                           float* __restrict__ out, int nrows) {
    int t = blockIdx.x * 256 + threadIdx.x;
    int row = t >> 4;
    if (row >= nrows) return;
    int c4 = t & 15;
    float4 v = *(const float4*)&in[(size_t)row * 64 + c4 * 4];
    float ss = v.x * v.x + v.y * v.y + v.z * v.z + v.w * v.w;
    ss += __shfl_xor(ss, 1, 64);
    ss += __shfl_xor(ss, 2, 64);
    ss += __shfl_xor(ss, 4, 64);
    ss += __shfl_xor(ss, 8, 64);
    if (c4 == 0) out[row] = -scale_p[0] * LOG2E * ss;
}

__global__ __launch_bounds__(256) void fb_main(
    const float* __restrict__ X, const float* __restrict__ svs,
    const float* __restrict__ scale_p, const float* __restrict__ a2,
    const float* __restrict__ b2, float* __restrict__ partials) {
    __shared__ __align__(16) unsigned char ldsA[128 * 128];
    __shared__ __align__(16) unsigned char ldsBf[128 * 128];
    const int tid = threadIdx.x, lane = tid & 63, wave = tid >> 6;
    const int rowbase = blockIdx.x * 128, nbase = blockIdx.y * 512;
    const float C1 = 2.0f * scale_p[0] * LOG2E;
    {
        int r16 = tid >> 4, c4 = tid & 15;
        for (int p = 0; p < 8; ++p) {
            int row = p * 16 + r16;
            float4 v = *(const float4*)&X[(size_t)(rowbase + row) * 64 + c4 * 4];
            uint2 pk;
            pk.x = (unsigned)f2bf(v.x) | ((unsigned)f2bf(v.y) << 16);
            pk.y = (unsigned)f2bf(v.z) | ((unsigned)f2bf(v.w) << 16);
            *(uint2*)(ldsA + swz(row, c4 * 8)) = pk;
        }
    }
    __syncthreads();
    short8 afrag[2][2];
    {
        int arow = wave * 32 + (lane & 15);
        int kb = (lane >> 4) * 16;
        for (int mf = 0; mf < 2; ++mf)
            for (int kf = 0; kf < 2; ++kf)
                afrag[mf][kf] = *(const short8*)(ldsA + swz(arow + mf * 16, kb + kf * 64));
    }
    float a2l[2][4];
    for (int mf = 0; mf < 2; ++mf)
        for (int q = 0; q < 4; ++q)
            a2l[mf][q] = a2[rowbase + wave * 32 + mf * 16 + (lane >> 4) * 4 + q];
    float s[2][4] = {{0.f, 0.f, 0.f, 0.f}, {0.f, 0.f, 0.f, 0.f}};
    for (int itq = 0; itq < 4; ++itq) {
        int nb0 = nbase + itq * 128;
        __syncthreads();
        {
            int r16 = tid >> 4, c4 = tid & 15;
            for (int p = 0; p < 8; ++p) {
                int row = p * 16 + r16;
                float4 v = *(const float4*)&svs[(size_t)(nb0 + row) * 64 + c4 * 4];
                uint2 pk;
                pk.x = (unsigned)f2bf(v.x) | ((unsigned)f2bf(v.y) << 16);
                pk.y = (unsigned)f2bf(v.z) | ((unsigned)f2bf(v.w) << 16);
                *(uint2*)(ldsBf + swz(row, c4 * 8)) = pk;
            }
        }
        float b2l[8];
        for (int nf = 0; nf < 8; ++nf)
            b2l[nf] = b2[nb0 + nf * 16 + (lane & 15)];
        __syncthreads();
        for (int nf = 0; nf < 8; ++nf) {
            int brow = nf * 16 + (lane & 15);
            int kb = (lane >> 4) * 16;
            short8 b0 = *(const short8*)(ldsBf + swz(brow, kb));
            short8 b1 = *(const short8*)(ldsBf + swz(brow, kb + 64));
            for (int mf = 0; mf < 2; ++mf) {
                f32x4 acc = {0.f, 0.f, 0.f, 0.f};
                acc = __builtin_amdgcn_mfma_f32_16x16x32_bf16(afrag[mf][0], b0, acc, 0, 0, 0);
                acc = __builtin_amdgcn_mfma_f32_16x16x32_bf16(afrag[mf][1], b1, acc, 0, 0, 0);
                for (int q = 0; q < 4; ++q) {
                    float e = __builtin_fmaf(C1, acc[q], a2l[mf][q]) + b2l[nf];
                    s[mf][q] += __builtin_amdgcn_exp2f(e);
                }
            }
        }
    }
    for (int mask = 1; mask < 16; mask <<= 1)
        for (int mf = 0; mf < 2; ++mf)
            for (int q = 0; q < 4; ++q)
                s[mf][q] += __shfl_xor(s[mf][q], mask, 64);
    if ((lane & 15) == 0) {
        for (int mf = 0; mf < 2; ++mf)
            for (int q = 0; q < 4; ++q) {
                int row = rowbase + wave * 32 + mf * 16 + (lane >> 4) * 4 + q;
                partials[(size_t)blockIdx.y * BTOT + row] = s[mf][q];
            }
    }
}

__global__ void fb_final(const float* __restrict__ partials,
                         const float* __restrict__ scale_p,
                         float* __restrict__ out) {
    int b = blockIdx.x * 256 + threadIdx.x;
    if (b >= BTOT) return;
    float total = 0.f;
    for (int sidx = 0; sidx < 128; ++sidx)
        total += partials[(size_t)sidx * BTOT + b];
    out[b] = logf(total) - logf((float)NTOT) + 32.0f * logf(scale_p[0] / PI_F);
}

extern "C" void kernel_launch(void* const* d_in, const int* in_sizes, int n_in,
                              void* d_out, int out_size, void* d_ws,
                              size_t ws_size, hipStream_t stream) {
    const float* X = (const float*)d_in[0];
    const float* svs = (const float*)d_in[1];
    const float* scale_p = (const float*)d_in[2];
    unsigned char* ws = (unsigned char*)d_ws;

    if (ws_size >= WS_NEEDED) {
        unsigned short* svs_bf = (unsigned short*)(ws + OFF_SVSBF);
        unsigned short* x_bf = (unsigned short*)(ws + OFF_XBF);
        float* eb2 = (float*)(ws + OFF_EB2);
        float* a2nat = (float*)(ws + OFF_A2);
        float* partials = (float*)(ws + OFF_PART);
        kde_prep<<<NTILES + 16, 256, 0, stream>>>(X, svs, scale_p, svs_bf, x_bf,
                                                  eb2, a2nat);
        kde_main10<<<2048, 512, 0, stream>>>(svs_bf, x_bf, eb2, partials);
        kde_final10<<<BTOT / 256, 256, 0, stream>>>(partials, a2nat, scale_p,
                                                    (float*)d_out);
    } else {
        float* wsf = (float*)d_ws;
        float* b2 = wsf;
        float* a2 = wsf + NTOT;
        float* partials = wsf + NTOT + BTOT;
        fb_rownorm<<<(NTOT * 16) / 256, 256, 0, stream>>>(svs, scale_p, b2, NTOT);
        fb_rownorm<<<(BTOT * 16) / 256, 256, 0, stream>>>(X, scale_p, a2, BTOT);
        dim3 grid(BTOT / 128, 128);
        fb_main<<<grid, 256, 0, stream>>>(X, svs, scale_p, a2, b2, partials);
        fb_final<<<BTOT / 256, 256, 0, stream>>>(partials, scale_p, (float*)d_out);
    }
}